// Round 10
// baseline (272.495 us; speedup 1.0000x reference)
//
#include <hip/hip_runtime.h>
#include <hip/hip_bf16.h>
#include <stdint.h>

#define D_EMB 128
#define D_NLP 768
#define NKC 12          // 12 k-chunks of 64

typedef __attribute__((ext_vector_type(8))) short bf16x8;
typedef __attribute__((ext_vector_type(4))) float f32x4;
typedef __attribute__((ext_vector_type(8))) unsigned short u16x8;

__device__ __forceinline__ unsigned short f2bf(float f) {
  unsigned u = __builtin_bit_cast(unsigned, f);
  u += 0x7fffu + ((u >> 16) & 1u);   // RTNE (NaN-free inputs)
  return (unsigned short)(u >> 16);
}

__device__ __forceinline__ bf16x8 pack8(const float4& a, const float4& b) {
  u16x8 v;
  v[0] = __builtin_bit_cast(unsigned short, __float2bfloat16(a.x));
  v[1] = __builtin_bit_cast(unsigned short, __float2bfloat16(a.y));
  v[2] = __builtin_bit_cast(unsigned short, __float2bfloat16(a.z));
  v[3] = __builtin_bit_cast(unsigned short, __float2bfloat16(a.w));
  v[4] = __builtin_bit_cast(unsigned short, __float2bfloat16(b.x));
  v[5] = __builtin_bit_cast(unsigned short, __float2bfloat16(b.y));
  v[6] = __builtin_bit_cast(unsigned short, __float2bfloat16(b.z));
  v[7] = __builtin_bit_cast(unsigned short, __float2bfloat16(b.w));
  return __builtin_bit_cast(bf16x8, v);
}

// ---- kernel W: w0 (128x768 f32) -> bf16 row-major; also init mn.
__global__ void kw(const float* __restrict__ w0, unsigned short* __restrict__ w0b,
                   int* __restrict__ mn) {
  int t = blockIdx.x * 256 + threadIdx.x;       // 12288 units
  if (t == 0) mn[0] = 0x7fffffff;
  if (t >= (D_EMB * D_NLP) / 8) return;
  const float4* src = (const float4*)(w0 + (size_t)t * 8);
  float4 v0 = src[0], v1 = src[1];
  u16x8 o;
  o[0] = f2bf(v0.x); o[1] = f2bf(v0.y); o[2] = f2bf(v0.z); o[3] = f2bf(v0.w);
  o[4] = f2bf(v1.x); o[5] = f2bf(v1.y); o[6] = f2bf(v1.z); o[7] = f2bf(v1.w);
  *(u16x8*)(w0b + (size_t)t * 8) = o;
}

// ---- kernel M: mn = min_e max(ei[0][e], ei[1][e])
__global__ void km(const int* __restrict__ ei, int E, int* __restrict__ mn) {
  int t = blockIdx.x * blockDim.x + threadIdx.x;
  int stride = gridDim.x * blockDim.x;
  int m = 0x7fffffff;
  for (int e = t; e < E; e += stride) {
    int a = ei[e], b = ei[E + e];
    int q = a > b ? a : b;
    m = q < m ? q : m;
  }
  #pragma unroll
  for (int off = 32; off; off >>= 1) {
    int o = __shfl_xor(m, off);
    m = o < m ? o : m;
  }
  if ((threadIdx.x & 63) == 0) atomicMin(mn, m);
}

// A: 4 float4 of chunk T (k = kg*8+[0,8) and 32+kg*8+[0,8))
#define LA(S, T) do {                                          \
    const float4* _p = (const float4*)(aBase + (T) * 64);      \
    S##0 = _p[0]; S##1 = _p[1]; S##2 = _p[8]; S##3 = _p[9];    \
  } while (0)

// B: 8 bf16x8 frags of chunk T (4 col-frags x 2 ks-halves), direct from L2.
#define LB(T) do {                                             \
    b00 = *(const bf16x8*)(bp0 + (T) * 64);                    \
    b01 = *(const bf16x8*)(bp1 + (T) * 64);                    \
    b02 = *(const bf16x8*)(bp2 + (T) * 64);                    \
    b03 = *(const bf16x8*)(bp3 + (T) * 64);                    \
    b10 = *(const bf16x8*)(bp0 + (T) * 64 + 32);               \
    b11 = *(const bf16x8*)(bp1 + (T) * 64 + 32);               \
    b12 = *(const bf16x8*)(bp2 + (T) * 64 + 32);               \
    b13 = *(const bf16x8*)(bp3 + (T) * 64 + 32);               \
  } while (0)

// One chunk: issue B(T) + A(T+1), fence, cvt A(T), 8 MFMAs. Compiler inserts
// precise counted vmcnt waits from dataflow; no barriers anywhere.
#define CH(T, CUR, NXT) do {                                                  \
    LB(T);                                                                    \
    if ((T) + 1 < NKC) LA(NXT, (T) + 1);                                      \
    __builtin_amdgcn_sched_barrier(0);                                        \
    bf16x8 _af0 = pack8(CUR##0, CUR##1);                                      \
    bf16x8 _af1 = pack8(CUR##2, CUR##3);                                      \
    acc[0] = __builtin_amdgcn_mfma_f32_16x16x32_bf16(_af0, b00, acc[0], 0, 0, 0); \
    acc[1] = __builtin_amdgcn_mfma_f32_16x16x32_bf16(_af0, b01, acc[1], 0, 0, 0); \
    acc[2] = __builtin_amdgcn_mfma_f32_16x16x32_bf16(_af0, b02, acc[2], 0, 0, 0); \
    acc[3] = __builtin_amdgcn_mfma_f32_16x16x32_bf16(_af0, b03, acc[3], 0, 0, 0); \
    acc[0] = __builtin_amdgcn_mfma_f32_16x16x32_bf16(_af1, b10, acc[0], 0, 0, 0); \
    acc[1] = __builtin_amdgcn_mfma_f32_16x16x32_bf16(_af1, b11, acc[1], 0, 0, 0); \
    acc[2] = __builtin_amdgcn_mfma_f32_16x16x32_bf16(_af1, b12, acc[2], 0, 0, 0); \
    acc[3] = __builtin_amdgcn_mfma_f32_16x16x32_bf16(_af1, b13, acc[3], 0, 0, 0); \
  } while (0)

// ---- kernel C: barrier-free, LDS-free. Block = 4 independent waves:
// wave (rt,ch) computes rows [blk*32+rt*16, +16) x cols [ch*64, +64).
// A: z0 global->named regs, 1 chunk ahead. B: w0b (192KB, L2-hot) per chunk.
// 16 free-running waves/CU, each ~12-16KB of loads in flight.
__global__ __launch_bounds__(256, 4) void kc(
    const float* __restrict__ z0, const float* __restrict__ z,
    const unsigned short* __restrict__ w0b, const float* __restrict__ w1,
    const float* __restrict__ prelu_a, float* __restrict__ sv,
    float* __restrict__ ta, float* __restrict__ tb, int N) {
  const int tid = threadIdx.x;
  const int lane = tid & 63;
  const int wave = tid >> 6;        // 0..3
  const int rt = wave >> 1;         // row-tile 0..1
  const int ch = wave & 1;          // col-half 0..1
  const int col = lane & 15;
  const int kg = lane >> 4;
  const int row0 = blockIdx.x * 32 + rt * 16;
  const int myrow = row0 + col;
  const int arow = min(myrow, N - 1);
  const float* aBase = z0 + (size_t)arow * D_NLP + kg * 8;
  const unsigned short* bp0 = w0b + (size_t)(ch * 64 + col) * D_NLP + kg * 8;
  const unsigned short* bp1 = bp0 + 16 * D_NLP;
  const unsigned short* bp2 = bp0 + 32 * D_NLP;
  const unsigned short* bp3 = bp0 + 48 * D_NLP;

  f32x4 acc[4];
  #pragma unroll
  for (int c = 0; c < 4; ++c) acc[c] = (f32x4){0.f, 0.f, 0.f, 0.f};

  float4 A0, A1, A2, A3, C0, C1, C2, C3;   // two named A sets (cur/next)
  #define AsA0 A0
  #define AsA1 A1
  #define AsA2 A2
  #define AsA3 A3
  #define AsB0 C0
  #define AsB1 C1
  #define AsB2 C2
  #define AsB3 C3
  bf16x8 b00, b01, b02, b03, b10, b11, b12, b13;

  LA(AsA, 0);
  CH(0, AsA, AsB);  CH(1, AsB, AsA);  CH(2, AsA, AsB);
  CH(3, AsB, AsA);  CH(4, AsA, AsB);  CH(5, AsB, AsA);
  CH(6, AsA, AsB);  CH(7, AsB, AsA);  CH(8, AsA, AsB);
  CH(9, AsB, AsA);  CH(10, AsA, AsB); CH(11, AsB, AsA);

  // epilogue: sv partial for this col-half: prelu * w1c, reduce 64 cols
  float ap = prelu_a[0];
  float ssum[4] = {0.f, 0.f, 0.f, 0.f};
  #pragma unroll
  for (int c = 0; c < 4; ++c) {
    float wc = w1[2 * D_EMB + ch * 64 + c * 16 + col];
    #pragma unroll
    for (int i = 0; i < 4; ++i) {
      float h = acc[c][i];
      float x = h >= 0.f ? h : ap * h;
      ssum[i] += x * wc;
    }
  }
  #pragma unroll
  for (int off = 1; off < 16; off <<= 1) {
    #pragma unroll
    for (int i = 0; i < 4; ++i) ssum[i] += __shfl_xor(ssum[i], off);
  }
  if (col == 0) {
    float* svh = sv + (size_t)ch * N;
    int rbase = row0 + kg * 4;            // C/D row = (lane>>4)*4 + i
    #pragma unroll
    for (int i = 0; i < 4; ++i) {
      int r = rbase + i;
      if (r < N) svh[r] = ssum[i];
    }
  }

  // fused kt (col-half 0 waves only): ta/tb for this wave's 16 rows
  if (ch == 0) {
    const float4* zp = (const float4*)(z + (size_t)arow * D_EMB + kg * 32);
    const float4* wa4 = (const float4*)(w1 + kg * 32);
    const float4* wb4 = (const float4*)(w1 + D_EMB + kg * 32);
    float pa = 0.f, pb = 0.f;
    #pragma unroll
    for (int i = 0; i < 8; ++i) {
      float4 zv = zp[i];
      float4 wa = wa4[i];
      float4 wb = wb4[i];
      pa += zv.x * wa.x + zv.y * wa.y + zv.z * wa.z + zv.w * wa.w;
      pb += zv.x * wb.x + zv.y * wb.y + zv.z * wb.z + zv.w * wb.w;
    }
    pa += __shfl_xor(pa, 16); pa += __shfl_xor(pa, 32);
    pb += __shfl_xor(pb, 16); pb += __shfl_xor(pb, 32);
    if (kg == 0 && myrow < N) { ta[myrow] = pa; tb[myrow] = pb; }
  }
}

// ---- kernel D: per-edge gather + add (sv = two col-half partials)
__global__ void kd(const int* __restrict__ ei, const int* __restrict__ mn,
                   const float* __restrict__ ta, const float* __restrict__ tb,
                   const float* __restrict__ sv, const float* __restrict__ b1,
                   float* __restrict__ out, int E, int N) {
  int e = blockIdx.x * blockDim.x + threadIdx.x;
  if (e >= E) return;
  int i0 = ei[e], i1 = ei[E + e];
  int q = (i0 > i1 ? i0 : i1) - mn[0];
  out[e] = ta[i0] + tb[i1] + sv[q] + sv[N + q] + b1[0];
}

extern "C" void kernel_launch(void* const* d_in, const int* in_sizes, int n_in,
                              void* d_out, int out_size, void* d_ws, size_t ws_size,
                              hipStream_t stream) {
  const float* z  = (const float*)d_in[0];
  const float* z0 = (const float*)d_in[1];
  const int*   ei = (const int*)d_in[2];
  const float* w0 = (const float*)d_in[3];
  const float* pa = (const float*)d_in[4];
  const float* w1 = (const float*)d_in[5];
  const float* b1 = (const float*)d_in[6];
  float* out = (float*)d_out;
  const int N = in_sizes[0] / D_EMB;
  const int E = in_sizes[2] / 2;

  // ws: [0,4) mn | [256,+192KB) w0b bf16 row-major | ta[N] | tb[N] | sv[2N]
  char* ws = (char*)d_ws;
  int* mn = (int*)ws;
  unsigned short* w0b = (unsigned short*)(ws + 256);
  float* ta = (float*)(ws + 256 + 196608);
  float* tb = ta + N;
  float* sv = tb + N;

  kw<<<(D_EMB * D_NLP / 8 + 255) / 256, 256, 0, stream>>>(w0, w0b, mn);
  km<<<256, 256, 0, stream>>>(ei, E, mn);
  kc<<<(N + 31) / 32, 256, 0, stream>>>(z0, z, w0b, w1, pa, sv, ta, tb, N);
  kd<<<(E + 255) / 256, 256, 0, stream>>>(ei, mn, ta, tb, sv, b1, out, E, N);
}

// Round 11
// 120.361 us; speedup vs baseline: 2.2640x; 2.2640x over previous
//
#include <hip/hip_runtime.h>
#include <hip/hip_bf16.h>
#include <stdint.h>

#define D_EMB 128
#define D_NLP 768
#define BM 64
#define BK 64
#define NKC (D_NLP / BK)   // 12 k-chunks

typedef __attribute__((ext_vector_type(8))) short bf16x8;
typedef __attribute__((ext_vector_type(4))) float f32x4;
typedef __attribute__((ext_vector_type(8))) unsigned short u16x8;

__device__ __forceinline__ unsigned short f2bf(float f) {
  unsigned u = __builtin_bit_cast(unsigned, f);
  u += 0x7fffu + ((u >> 16) & 1u);   // RTNE (NaN-free inputs)
  return (unsigned short)(u >> 16);
}

__device__ __forceinline__ bf16x8 pack8(const float4& a, const float4& b) {
  u16x8 v;
  v[0] = __builtin_bit_cast(unsigned short, __float2bfloat16(a.x));
  v[1] = __builtin_bit_cast(unsigned short, __float2bfloat16(a.y));
  v[2] = __builtin_bit_cast(unsigned short, __float2bfloat16(a.z));
  v[3] = __builtin_bit_cast(unsigned short, __float2bfloat16(a.w));
  v[4] = __builtin_bit_cast(unsigned short, __float2bfloat16(b.x));
  v[5] = __builtin_bit_cast(unsigned short, __float2bfloat16(b.y));
  v[6] = __builtin_bit_cast(unsigned short, __float2bfloat16(b.z));
  v[7] = __builtin_bit_cast(unsigned short, __float2bfloat16(b.w));
  return __builtin_bit_cast(bf16x8, v);
}

// ---- kernel W: w0 (128x768 f32) -> bf16, pre-swizzled per 64-k chunk (B path).
__global__ void kw(const float* __restrict__ w0, unsigned short* __restrict__ w0s,
                   int* __restrict__ mn) {
  if (blockIdx.x == 0 && threadIdx.x == 0) mn[0] = 0x7fffffff;
  int t = blockIdx.x * 256 + threadIdx.x;       // 12288 units
  if (t >= (D_EMB * D_NLP) / 8) return;
  int u = t & 7, row = (t >> 3) & 127, kc = t >> 10;
  const float4* src = (const float4*)(w0 + (size_t)row * D_NLP + kc * 64 + ((u ^ (row & 7)) * 8));
  float4 v0 = src[0], v1 = src[1];
  u16x8 o;
  o[0] = f2bf(v0.x); o[1] = f2bf(v0.y); o[2] = f2bf(v0.z); o[3] = f2bf(v0.w);
  o[4] = f2bf(v1.x); o[5] = f2bf(v1.y); o[6] = f2bf(v1.z); o[7] = f2bf(v1.w);
  *(u16x8*)(w0s + (size_t)t * 8) = o;
}

// ---- kernel M: mn = min_e max(ei[0][e], ei[1][e])
__global__ void km(const int* __restrict__ ei, int E, int* __restrict__ mn) {
  int t = blockIdx.x * blockDim.x + threadIdx.x;
  int stride = gridDim.x * blockDim.x;
  int m = 0x7fffffff;
  for (int e = t; e < E; e += stride) {
    int a = ei[e], b = ei[E + e];
    int q = a > b ? a : b;
    m = q < m ? q : m;
  }
  #pragma unroll
  for (int off = 32; off; off >>= 1) {
    int o = __shfl_xor(m, off);
    m = o < m ? o : m;
  }
  if ((threadIdx.x & 63) == 0) atomicMin(mn, m);
}

// ---- kernel C: A staged through LDS with DENSE-LINE global reads.
// Each global_load_lds instruction reads 4 rows x 256B COMPLETE runs (vs 16
// half-used lines before). Swizzle is folded into the per-lane GLOBAL source
// address; LDS dest stays linear. A ring-3 (wave-local rows: no barrier
// needed for A), B ring-2 (R5's proven path). In-flight A data uses ZERO
// VGPRs. LDS 48+32=80KB -> 2 blocks/CU.
__global__ __launch_bounds__(256) void kc(
    const float* __restrict__ z0, const float* __restrict__ z,
    const unsigned short* __restrict__ w0s, const float* __restrict__ w1,
    const float* __restrict__ prelu_a, float* __restrict__ sv,
    float* __restrict__ ta, float* __restrict__ tb, int N) {
  extern __shared__ char smem[];
  float* Al = (float*)smem;                          // 3 x 64rows x 64f = 48KB
  unsigned short* Bl = (unsigned short*)(smem + 49152);  // 2 x 8192 = 32KB

  const int tid = threadIdx.x;
  const int lane = tid & 63;
  const int wave = tid >> 6;
  const int kg = lane >> 4;        // 0..3
  const int col = lane & 15;
  const int s16 = lane & 15;       // A-stage: 16B-unit within row slice
  const int hl = lane >> 4;        // A-stage: row within 4-row group
  const int r0 = blockIdx.x * BM;
  const int myrow = r0 + wave * 16 + col;
  const int arow_g = min(myrow, N - 1);

  // A-stage source pointers: instr p covers rows wave*16 + p*4 + hl,
  // unit cu = s16 ^ (rlocal&7)  (pre-swizzled source -> linear LDS dest).
  const float* aSrc[4];
  #pragma unroll
  for (int p = 0; p < 4; ++p) {
    int rl = p * 4 + hl;                       // row within wave's 16
    int rg = min(r0 + wave * 16 + rl, N - 1);
    int cu = s16 ^ (rl & 7);
    aSrc[p] = z0 + (size_t)rg * D_NLP + cu * 4;
  }

  auto stageA = [&](int t, int buf) {
    #pragma unroll
    for (int p = 0; p < 4; ++p) {
      __builtin_amdgcn_global_load_lds(
          (const __attribute__((address_space(1))) void*)(aSrc[p] + t * BK),
          (__attribute__((address_space(3))) void*)&Al[buf * 4096 + (wave * 16 + p * 4) * 64],
          16, 0, 0);
    }
  };

  auto stageB = [&](int t, int buf) {
    const unsigned short* g = w0s + (size_t)t * (D_EMB * BK) + (size_t)tid * 8;
    #pragma unroll
    for (int p = 0; p < 4; ++p) {
      __builtin_amdgcn_global_load_lds(
          (const __attribute__((address_space(1))) void*)(g + p * 256 * 8),
          (__attribute__((address_space(3))) void*)&Bl[buf * 8192 + (wave * 64 + p * 256) * 8],
          16, 0, 0);
    }
  };

  f32x4 acc[8];
  #pragma unroll
  for (int c = 0; c < 8; ++c) acc[c] = (f32x4){0.f, 0.f, 0.f, 0.f};

  // prologue: B(0), A(0), A(1) in flight (12 ops; B first for in-order waits)
  stageB(0, 0);
  stageA(0, 0);
  stageA(1, 1);

  const int arow_l = (wave * 16 + col) * 64;   // A LDS row base (floats)
  const int asw = col & 7;

  #pragma unroll
  for (int t = 0; t < NKC; ++t) {
    // wait: chunk t's A+B landed (newest 4 = A(t+1) may fly)
    if (t < NKC - 1) asm volatile("s_waitcnt vmcnt(4)" ::: "memory");
    else             asm volatile("s_waitcnt vmcnt(0)" ::: "memory");
    __builtin_amdgcn_s_barrier();
    if (t + 1 < NKC) stageB(t + 1, (t + 1) & 1);
    if (t + 2 < NKC) stageA(t + 2, (t + 2) % 3);
    __builtin_amdgcn_sched_barrier(0);

    const float* Ab = Al + (t % 3) * 4096;
    const unsigned short* Bbuf = Bl + (t & 1) * 8192;
    #pragma unroll
    for (int ks = 0; ks < 2; ++ks) {
      int u0 = ks * 8 + kg * 2;
      float4 lo = *(const float4*)&Ab[arow_l + ((u0)     ^ asw) * 4];
      float4 hi = *(const float4*)&Ab[arow_l + ((u0 + 1) ^ asw) * 4];
      bf16x8 af = pack8(lo, hi);
      #pragma unroll
      for (int c = 0; c < 8; ++c) {
        int brow = c * 16 + col;
        bf16x8 bfr = *(const bf16x8*)&Bbuf[(brow * 8 + ((ks * 4 + kg) ^ (brow & 7))) * 8];
        acc[c] = __builtin_amdgcn_mfma_f32_16x16x32_bf16(af, bfr, acc[c], 0, 0, 0);
      }
    }
  }

  // epilogue 1: prelu + * w1c[col-block], reduce the 16 cols held per lane-group
  float ap = prelu_a[0];
  float ssum[4] = {0.f, 0.f, 0.f, 0.f};
  #pragma unroll
  for (int c = 0; c < 8; ++c) {
    float wc = w1[2 * D_EMB + c * 16 + col];
    #pragma unroll
    for (int i = 0; i < 4; ++i) {
      float h = acc[c][i];
      float x = h >= 0.f ? h : ap * h;
      ssum[i] += x * wc;
    }
  }
  #pragma unroll
  for (int off = 1; off < 16; off <<= 1) {
    #pragma unroll
    for (int i = 0; i < 4; ++i) ssum[i] += __shfl_xor(ssum[i], off);
  }
  if (col == 0) {
    int rbase = r0 + wave * 16 + kg * 4;   // C/D row = (lane>>4)*4 + i
    #pragma unroll
    for (int i = 0; i < 4; ++i) {
      int r = rbase + i;
      if (r < N) sv[r] = ssum[i];
    }
  }

  // epilogue 2 (fused kt): ta/tb for this block's 64 rows
  {
    const float* zp = z + (size_t)arow_g * D_EMB + kg * 32;
    const float4* wa4 = (const float4*)(w1 + kg * 32);
    const float4* wb4 = (const float4*)(w1 + D_EMB + kg * 32);
    float pa = 0.f, pb = 0.f;
    #pragma unroll
    for (int i = 0; i < 8; ++i) {
      float4 zv = ((const float4*)zp)[i];
      float4 wa = wa4[i];
      float4 wb = wb4[i];
      pa += zv.x * wa.x + zv.y * wa.y + zv.z * wa.z + zv.w * wa.w;
      pb += zv.x * wb.x + zv.y * wb.y + zv.z * wb.z + zv.w * wb.w;
    }
    pa += __shfl_xor(pa, 16); pa += __shfl_xor(pa, 32);
    pb += __shfl_xor(pb, 16); pb += __shfl_xor(pb, 32);
    if (kg == 0 && myrow < N) { ta[myrow] = pa; tb[myrow] = pb; }
  }
}

// ---- kernel D: per-edge gather + add
__global__ void kd(const int* __restrict__ ei, const int* __restrict__ mn,
                   const float* __restrict__ ta, const float* __restrict__ tb,
                   const float* __restrict__ sv, const float* __restrict__ b1,
                   float* __restrict__ out, int E) {
  int e = blockIdx.x * blockDim.x + threadIdx.x;
  if (e >= E) return;
  int i0 = ei[e], i1 = ei[E + e];
  int q = (i0 > i1 ? i0 : i1) - mn[0];
  out[e] = ta[i0] + tb[i1] + sv[q] + b1[0];
}

extern "C" void kernel_launch(void* const* d_in, const int* in_sizes, int n_in,
                              void* d_out, int out_size, void* d_ws, size_t ws_size,
                              hipStream_t stream) {
  const float* z  = (const float*)d_in[0];
  const float* z0 = (const float*)d_in[1];
  const int*   ei = (const int*)d_in[2];
  const float* w0 = (const float*)d_in[3];
  const float* pa = (const float*)d_in[4];
  const float* w1 = (const float*)d_in[5];
  const float* b1 = (const float*)d_in[6];
  float* out = (float*)d_out;
  const int N = in_sizes[0] / D_EMB;
  const int E = in_sizes[2] / 2;

  // ws: [0,4) mn | [256,+192KB) w0s bf16 pre-swizzled | ta[N], tb[N], sv[N]
  char* ws = (char*)d_ws;
  int* mn = (int*)ws;
  unsigned short* w0s = (unsigned short*)(ws + 256);
  float* ta = (float*)(ws + 256 + 196608);
  float* tb = ta + N;
  float* sv = tb + N;

  hipFuncSetAttribute((const void*)kc,
                      hipFuncAttributeMaxDynamicSharedMemorySize, 81920);

  kw<<<(D_EMB * D_NLP / 8 + 255) / 256, 256, 0, stream>>>(w0, w0s, mn);
  km<<<256, 256, 0, stream>>>(ei, E, mn);
  kc<<<(N + BM - 1) / BM, 256, 81920, stream>>>(z0, z, w0s, w1, pa, sv, ta, tb, N);
  kd<<<(E + 255) / 256, 256, 0, stream>>>(ei, mn, ta, tb, sv, b1, out, E);
}